// Round 11
// baseline (4843.424 us; speedup 1.0000x reference)
//
#include <hip/hip_runtime.h>
#include <cstddef>

#define EPS 1e-5f

constexpr int Bsz = 256;
constexpr int Nn  = 100;
constexpr int Cc  = 512;
constexpr int BN_ROWS = Bsz * Nn; // 25600

__device__ __forceinline__ void gload_lds16(const void* g, void* l) {
    __builtin_amdgcn_global_load_lds(
        (const __attribute__((address_space(1))) void*)g,
        (__attribute__((address_space(3))) void*)l, 16, 0, 0);
}

// ---------------- per-column stats over M rows (M <= 256), grid = Ccols ----------------
__global__ void colstats_kernel(const float* __restrict__ x, int M, int Ccols,
                                const float* __restrict__ g, const float* __restrict__ bb,
                                float* __restrict__ s, float* __restrict__ t) {
    int c = blockIdx.x;
    int r = threadIdx.x;
    float v = (r < M) ? x[(size_t)r * Ccols + c] : 0.f;
    __shared__ float ssum[256], ssq[256];
    ssum[r] = v; ssq[r] = v * v;
    __syncthreads();
    for (int off = 128; off > 0; off >>= 1) {
        if (r < off) { ssum[r] += ssum[r + off]; ssq[r] += ssq[r + off]; }
        __syncthreads();
    }
    if (r == 0) {
        float m   = ssum[0] / M;
        float var = ssq[0] / M - m * m;
        float sc  = g[c] * rsqrtf(var + EPS);
        s[c] = sc;
        t[c] = bb[c] - m * sc;
    }
}

// ---------------- small per-node-channel stats (pos: D=4), grid = Nn ----------------
__global__ void chstats_kernel(const float* __restrict__ x, int D,
                               const float* __restrict__ g, const float* __restrict__ bb,
                               float* __restrict__ s, float* __restrict__ t) {
    int n = blockIdx.x;
    int tid = threadIdx.x;
    int total = Bsz * D;
    float sum = 0.f, sq = 0.f;
    for (int idx = tid; idx < total; idx += blockDim.x) {
        int b = idx / D, d = idx - b * D;
        float v = x[((size_t)b * Nn + n) * D + d];
        sum += v; sq += v * v;
    }
    __shared__ float ssum[256], ssq[256];
    ssum[tid] = sum; ssq[tid] = sq;
    __syncthreads();
    for (int off = 128; off > 0; off >>= 1) {
        if (tid < off) { ssum[tid] += ssum[tid + off]; ssq[tid] += ssq[tid + off]; }
        __syncthreads();
    }
    if (tid == 0) {
        float m   = ssum[0] / total;
        float var = ssq[0] / total - m * m;
        float sc  = g[n] * rsqrtf(var + EPS);
        s[n] = sc;
        t[n] = bb[n] - m * sc;
    }
}

// ---------------- node-emb channel stats, two-stage: grid (100, 16) ----------------
__global__ void chstats_part_kernel(const float* __restrict__ x, float* __restrict__ npart) {
    int n = blockIdx.x, chunk = blockIdx.y;
    int tid = threadIdx.x;
    float sum = 0.f, sq = 0.f;
    for (int i = tid; i < 3072; i += 256) {
        int rrow = i / 192;
        int q = i - rrow * 192;
        float4 f = *(const float4*)(x + ((size_t)(chunk * 16 + rrow) * Nn + n) * 768 + q * 4);
        sum += f.x + f.y + f.z + f.w;
        sq  += f.x * f.x + f.y * f.y + f.z * f.z + f.w * f.w;
    }
    __shared__ float ss[256], s2[256];
    ss[tid] = sum; s2[tid] = sq;
    __syncthreads();
    for (int off = 128; off > 0; off >>= 1) {
        if (tid < off) { ss[tid] += ss[tid + off]; s2[tid] += s2[tid + off]; }
        __syncthreads();
    }
    if (tid == 0) {
        npart[chunk * 200 + n] = ss[0];
        npart[chunk * 200 + 100 + n] = s2[0];
    }
}

__global__ void chstats_fin_kernel(const float* __restrict__ npart,
                                   const float* __restrict__ g, const float* __restrict__ bb,
                                   float* __restrict__ s, float* __restrict__ t) {
    int n = threadIdx.x;
    if (n >= 100) return;
    float sum = 0.f, sq = 0.f;
    for (int c = 0; c < 16; c++) {
        sum += npart[c * 200 + n];
        sq  += npart[c * 200 + 100 + n];
    }
    const float total = 256.f * 768.f;
    float m   = sum / total;
    float var = sq / total - m * m;
    float sc  = g[n] * rsqrtf(var + EPS);
    s[n] = sc;
    t[n] = bb[n] - m * sc;
}

// ---------------- transpose fcgat weights (480x768 -> 768x512 zero-padded) ----------------
__global__ void transpose_w_kernel(const float* __restrict__ w, const float* __restrict__ bias,
                                   float* __restrict__ WT, float* __restrict__ pb) {
    __shared__ float tile[32][33];
    int kb = blockIdx.x * 32, nb = blockIdx.y * 32;
    int tx = threadIdx.x & 31, ty = threadIdx.x >> 5; // 32x8
#pragma unroll
    for (int i = 0; i < 4; i++) {
        int n = nb + ty + i * 8;
        tile[ty + i * 8][tx] = (n < 480) ? w[(size_t)n * 768 + kb + tx] : 0.f;
    }
    __syncthreads();
#pragma unroll
    for (int i = 0; i < 4; i++) {
        int k = kb + ty + i * 8;
        WT[(size_t)k * 512 + nb + tx] = tile[tx][ty + i * 8];
    }
    if (blockIdx.x == 0 && threadIdx.x < 32) {
        int n = nb + threadIdx.x;
        pb[n] = (n < 480) ? bias[n] : 0.f;
    }
}

// ========== single-buffer 128x128 fp32 GEMM, 8x8 micro-tile, K-step KS ==========
// 1D grid with XCD-bijective swizzle. grid = nbm * (1<<BYSHIFT), nbm%8==0.
// NORM: 0 none, 2 per-row (s[m % mod]).
// TB=true : B is (N x K) row-major (reg-staged, N-guarded)
// TB=false: B is (K x N) row-major (global_load_lds staged)
template <int NORM, bool ELU, bool TB, int KS, int BYSHIFT>
__global__ __launch_bounds__(256) void gemm128_kernel(
    const float* __restrict__ A, const float* __restrict__ B0,
    const float* __restrict__ B1, int nsplit,
    const float* __restrict__ bias,
    const float* __restrict__ s, const float* __restrict__ t,
    int M, int N, int K, int lda, int ldb, int mod,
    float* __restrict__ C, int ldc, int c_off) {
    constexpr int BS = TB ? 132 : 128;
    __shared__ float As[KS * 132];
    __shared__ float Bs[KS * BS];

    int bid = blockIdx.x;
    int xcd = bid & 7;
    int l = bid >> 3;
    int by = l & ((1 << BYSHIFT) - 1);
    int bmi = l >> BYSHIFT;
    int bm_per_xcd = (int)(gridDim.x >> (3 + BYSHIFT));
    int bm = (xcd * bm_per_xcd + bmi) * 128;

    const float* B = (by < nsplit) ? B0 : B1;
    int bn = (by < nsplit ? by : by - nsplit) * 128;
    int outcol0 = c_off + by * 128;

    int tid = threadIdx.x;
    int lane = tid & 63, wave = tid >> 6;
    int tx = tid & 15, ty = tid >> 4;

    float acc[8][8] = {};

    for (int k0 = 0; k0 < K; k0 += KS) {
        // ---- stage B async first (hides under A reg work) ----
        if constexpr (!TB) {
#pragma unroll
            for (int i = 0; i < KS / 8; i++) {
                int r = i * 8 + wave * 2 + (lane >> 5);
                gload_lds16(B + (size_t)(k0 + r) * ldb + bn + (lane & 31) * 4,
                            (char*)&Bs[r * BS]);
            }
        }
        // ---- stage A (reg -> LDS transpose) ----
#pragma unroll
        for (int i = 0; i < KS / 8; i++) {
            int id = tid + i * 256;
            int row = id / (KS / 4), q = id % (KS / 4);
            int gr = bm + row;
            float4 f = *(const float4*)(A + (size_t)gr * lda + k0 + q * 4);
            if constexpr (NORM == 2) {
                int n_ = gr % mod; float sc = s[n_], sh = t[n_];
                f.x = f.x * sc + sh; f.y = f.y * sc + sh;
                f.z = f.z * sc + sh; f.w = f.w * sc + sh;
            }
            As[(q * 4 + 0) * 132 + row] = f.x;
            As[(q * 4 + 1) * 132 + row] = f.y;
            As[(q * 4 + 2) * 132 + row] = f.z;
            As[(q * 4 + 3) * 132 + row] = f.w;
        }
        if constexpr (TB) {
#pragma unroll
            for (int i = 0; i < KS / 8; i++) {
                int id = tid + i * 256;
                int row = id / (KS / 4), q = id % (KS / 4);
                int gn = bn + row;
                float4 f = make_float4(0.f, 0.f, 0.f, 0.f);
                if (gn < N) f = *(const float4*)(B + (size_t)gn * ldb + k0 + q * 4);
                Bs[(q * 4 + 0) * BS + row] = f.x;
                Bs[(q * 4 + 1) * BS + row] = f.y;
                Bs[(q * 4 + 2) * BS + row] = f.z;
                Bs[(q * 4 + 3) * BS + row] = f.w;
            }
        }
        __syncthreads();
#pragma unroll 16
        for (int kk = 0; kk < KS; kk++) {
            float4 a0 = *(const float4*)&As[kk * 132 + ty * 4];
            float4 a1 = *(const float4*)&As[kk * 132 + ty * 4 + 64];
            float4 b0 = *(const float4*)&Bs[kk * BS + tx * 4];
            float4 b1 = *(const float4*)&Bs[kk * BS + tx * 4 + 64];
            float av[8] = {a0.x, a0.y, a0.z, a0.w, a1.x, a1.y, a1.z, a1.w};
            float bv[8] = {b0.x, b0.y, b0.z, b0.w, b1.x, b1.y, b1.z, b1.w};
#pragma unroll
            for (int i = 0; i < 8; i++)
#pragma unroll
                for (int j = 0; j < 8; j++)
                    acc[i][j] = fmaf(av[i], bv[j], acc[i][j]);
        }
        __syncthreads();
    }

#pragma unroll
    for (int i = 0; i < 8; i++) {
        int r = ty * 4 + (i & 3) + ((i & 4) ? 64 : 0);
        int gr = bm + r;
        if (gr >= M) continue;
        float* crow = C + (size_t)gr * ldc + outcol0;
#pragma unroll
        for (int h = 0; h < 2; h++) {
            int cl = tx * 4 + h * 64;
            int gcol = bn + cl;
            if constexpr (TB) { if (gcol >= N) continue; }
            float4 o;
            o.x = acc[i][h * 4 + 0]; o.y = acc[i][h * 4 + 1];
            o.z = acc[i][h * 4 + 2]; o.w = acc[i][h * 4 + 3];
            if (bias) {
                o.x += bias[gcol]; o.y += bias[gcol + 1];
                o.z += bias[gcol + 2]; o.w += bias[gcol + 3];
            }
            if constexpr (ELU) {
                o.x = o.x > 0.f ? o.x : expm1f(o.x);
                o.y = o.y > 0.f ? o.y : expm1f(o.y);
                o.z = o.z > 0.f ? o.z : expm1f(o.z);
                o.w = o.w > 0.f ? o.w : expm1f(o.w);
            }
            *(float4*)(crow + cl) = o;
        }
    }
}

// ========== 128x256-tile fp32 GEMM, 8x16 micro-tile ==========
// LDS-BW cap = 256/288 = 0.89 (vs 0.67 for 8x8). __launch_bounds__(256,2) lets the
// allocator use up to 256 VGPR/wave so acc[8][16] (128 VGPR) does NOT spill
// (round-9 failure mode: default occupancy target capped VGPR at 100 -> scratch).
// B is (K x N) k-major, staged via global_load_lds. grid = nbm*4, XCD-swizzled.
template <int KS>
__global__ __launch_bounds__(256, 2) void gemm256_kernel(
    const float* __restrict__ A, const float* __restrict__ B0,
    const float* __restrict__ B1, int nsplit,
    int M, int K, int lda, int ldb,
    float* __restrict__ C, int ldc) {
    __shared__ float As[KS * 132];
    __shared__ float Bs[KS * 260];

    int bid = blockIdx.x;
    int xcd = bid & 7;
    int l = bid >> 3;
    int by = l & 3;
    int bmi = l >> 2;
    int bm_per_xcd = (int)(gridDim.x >> 5);
    int bm = (xcd * bm_per_xcd + bmi) * 128;

    const float* B = (by < nsplit) ? B0 : B1;
    int bn = (by < nsplit ? by : by - nsplit) * 256;
    int outcol0 = by * 256;

    int tid = threadIdx.x;
    int lane = tid & 63, wave = tid >> 6;
    int tx = tid & 15, ty = tid >> 4;

    float acc[8][16] = {};

    for (int k0 = 0; k0 < K; k0 += KS) {
        // B async staging first: one 256-float row per gload (1 KB per wave-instr)
#pragma unroll
        for (int i = 0; i < KS / 4; i++) {
            int r = i * 4 + wave;
            gload_lds16(B + (size_t)(k0 + r) * ldb + bn + lane * 4,
                        (char*)&Bs[r * 260]);
        }
        // A reg->LDS transpose
#pragma unroll
        for (int i = 0; i < KS / 8; i++) {
            int id = tid + i * 256;
            int row = id / (KS / 4), q = id % (KS / 4);
            float4 f = *(const float4*)(A + (size_t)(bm + row) * lda + k0 + q * 4);
            As[(q * 4 + 0) * 132 + row] = f.x;
            As[(q * 4 + 1) * 132 + row] = f.y;
            As[(q * 4 + 2) * 132 + row] = f.z;
            As[(q * 4 + 3) * 132 + row] = f.w;
        }
        __syncthreads();
#pragma unroll 4
        for (int kk = 0; kk < KS; kk++) {
            float4 a0 = *(const float4*)&As[kk * 132 + ty * 4];
            float4 a1 = *(const float4*)&As[kk * 132 + ty * 4 + 64];
            float4 b0 = *(const float4*)&Bs[kk * 260 + tx * 4];
            float4 b1 = *(const float4*)&Bs[kk * 260 + tx * 4 + 64];
            float4 b2 = *(const float4*)&Bs[kk * 260 + tx * 4 + 128];
            float4 b3 = *(const float4*)&Bs[kk * 260 + tx * 4 + 192];
            float av[8] = {a0.x, a0.y, a0.z, a0.w, a1.x, a1.y, a1.z, a1.w};
            float bv[16] = {b0.x, b0.y, b0.z, b0.w, b1.x, b1.y, b1.z, b1.w,
                            b2.x, b2.y, b2.z, b2.w, b3.x, b3.y, b3.z, b3.w};
#pragma unroll
            for (int i = 0; i < 8; i++)
#pragma unroll
                for (int j = 0; j < 16; j++)
                    acc[i][j] = fmaf(av[i], bv[j], acc[i][j]);
        }
        __syncthreads();
    }

#pragma unroll
    for (int i = 0; i < 8; i++) {
        int r = ty * 4 + (i & 3) + ((i & 4) ? 64 : 0);
        int gr = bm + r;
        float* crow = C + (size_t)gr * ldc + outcol0;
#pragma unroll
        for (int h = 0; h < 4; h++) {
            float4 o;
            o.x = acc[i][h * 4 + 0]; o.y = acc[i][h * 4 + 1];
            o.z = acc[i][h * 4 + 2]; o.w = acc[i][h * 4 + 3];
            *(float4*)(crow + tx * 4 + h * 64) = o;
        }
    }
}

// ---------------- generic 64x64 tiled GEMM (small heads) ----------------
template <int NORM, bool ELU, bool TB>
__global__ void gemm_kernel(const float* __restrict__ A, const float* __restrict__ B,
                            const float* __restrict__ bias,
                            const float* __restrict__ s, const float* __restrict__ t,
                            int M, int N, int K, int lda, int ldb, int mod,
                            float* __restrict__ Cout, int ldc, int c_off) {
    __shared__ float As[16][65];
    __shared__ float Bs[16][65];

    int bm = blockIdx.x * 64, bn = blockIdx.y * 64;
    int tid = threadIdx.x;
    int tm = (tid >> 4) << 2;
    int tn = (tid & 15) << 2;
    float acc[4][4] = {};

    for (int k0 = 0; k0 < K; k0 += 16) {
#pragma unroll
        for (int i = 0; i < 4; i++) {
            int idx = tid + i * 256;
            {
                int rr = idx >> 4, kk = idx & 15;
                int gr = bm + rr, gk = k0 + kk;
                float av = 0.f;
                if (gr < M && gk < K) {
                    av = A[(size_t)gr * lda + gk];
                    if constexpr (NORM == 1) av = av * s[gk] + t[gk];
                    else if constexpr (NORM == 2) { int n_ = gr % mod; av = av * s[n_] + t[n_]; }
                }
                As[kk][rr] = av;
            }
            if constexpr (TB) {
                int nn = idx >> 4, kk = idx & 15;
                int gn = bn + nn, gk = k0 + kk;
                Bs[kk][nn] = (gn < N && gk < K) ? B[(size_t)gn * ldb + gk] : 0.f;
            } else {
                int kk = idx >> 6, nn = idx & 63;
                int gn = bn + nn, gk = k0 + kk;
                Bs[kk][nn] = (gn < N && gk < K) ? B[(size_t)gk * ldb + gn] : 0.f;
            }
        }
        __syncthreads();
#pragma unroll
        for (int kk = 0; kk < 16; kk++) {
            float a0[4], b0[4];
#pragma unroll
            for (int i = 0; i < 4; i++) a0[i] = As[kk][tm + i];
#pragma unroll
            for (int j = 0; j < 4; j++) b0[j] = Bs[kk][tn + j];
#pragma unroll
            for (int i = 0; i < 4; i++)
#pragma unroll
                for (int j = 0; j < 4; j++)
                    acc[i][j] = fmaf(a0[i], b0[j], acc[i][j]);
        }
        __syncthreads();
    }

#pragma unroll
    for (int i = 0; i < 4; i++) {
        int gr = bm + tm + i;
        if (gr >= M) continue;
#pragma unroll
        for (int j = 0; j < 4; j++) {
            int gn = bn + tn + j;
            if (gn >= N) continue;
            float v = acc[i][j] + (bias ? bias[gn] : 0.f);
            if constexpr (ELU) v = v > 0.f ? v : expm1f(v);
            Cout[(size_t)gr * ldc + c_off + gn] = v;
        }
    }
}

// ---------------- compose (all 8 GCN blocks): z = blk*2 + which ----------------
__global__ __launch_bounds__(256) void compose_kernel(
    const float* __restrict__ thw, const float* __restrict__ phw,
    const float* __restrict__ gw, const float* __restrict__ Ww,
    float* __restrict__ Mw_all, float* __restrict__ WGT_all) {
    __shared__ float As[32][33];
    __shared__ float Bs[32][68];
    int blk = blockIdx.z >> 1;
    int z = blockIdx.z & 1;
    size_t woff = (size_t)blk * Cc * Cc;
    const float* A = (z ? gw : thw) + woff;
    const float* ph = phw + woff;
    const float* W = Ww + woff;
    int bm = blockIdx.x * 32, bn = blockIdx.y * 64;
    int tid = threadIdx.x;
    int tm = (tid >> 4) * 2, tn = (tid & 15) * 4;
    float acc[2][4] = {};

    for (int k0 = 0; k0 < Cc; k0 += 32) {
#pragma unroll
        for (int i = 0; i < 4; i++) {
            int id = tid + i * 256;
            int kk = id >> 5, m = id & 31;
            As[kk][m] = A[(size_t)(k0 + kk) * Cc + bm + m];
        }
#pragma unroll
        for (int i = 0; i < 8; i++) {
            int id = tid + i * 256;
            if (z == 0) {
                int kk = id >> 6, n = id & 63;
                Bs[kk][n] = ph[(size_t)(k0 + kk) * Cc + bn + n];
            } else {
                int n = id >> 5, kk = id & 31;
                Bs[kk][n] = W[(size_t)(bn + n) * Cc + k0 + kk];
            }
        }
        __syncthreads();
#pragma unroll
        for (int kk = 0; kk < 32; kk++) {
            float a0 = As[kk][tm], a1 = As[kk][tm + 1];
            float4 b4 = *(const float4*)&Bs[kk][tn];
            acc[0][0] = fmaf(a0, b4.x, acc[0][0]);
            acc[0][1] = fmaf(a0, b4.y, acc[0][1]);
            acc[0][2] = fmaf(a0, b4.z, acc[0][2]);
            acc[0][3] = fmaf(a0, b4.w, acc[0][3]);
            acc[1][0] = fmaf(a1, b4.x, acc[1][0]);
            acc[1][1] = fmaf(a1, b4.y, acc[1][1]);
            acc[1][2] = fmaf(a1, b4.z, acc[1][2]);
            acc[1][3] = fmaf(a1, b4.w, acc[1][3]);
        }
        __syncthreads();
    }
    float* out = (z ? WGT_all : Mw_all) + woff;
    *(float4*)&out[(size_t)(bm + tm) * Cc + bn + tn] =
        make_float4(acc[0][0], acc[0][1], acc[0][2], acc[0][3]);
    *(float4*)&out[(size_t)(bm + tm + 1) * Cc + bn + tn] =
        make_float4(acc[1][0], acc[1][1], acc[1][2], acc[1][3]);
}

// ---------------- q2/cconst for all blocks: grid (512, 16) ----------------
__global__ void qc_kernel(const float* __restrict__ phw, const float* __restrict__ thb,
                          const float* __restrict__ Ww, const float* __restrict__ gb,
                          const float* __restrict__ Wb,
                          float* __restrict__ q2a, float* __restrict__ cca) {
    int blk = blockIdx.y >> 1;
    int type = blockIdx.y & 1;
    int c = blockIdx.x;
    int l = threadIdx.x; // 64
    float acc = 0.f;
    if (type == 0) {
        const float* phi = phw + (size_t)blk * Cc * Cc;
        const float* tb = thb + (size_t)blk * Cc;
        for (int j = l; j < Cc; j += 64) acc += phi[(size_t)j * Cc + c] * tb[j];
        for (int off = 32; off > 0; off >>= 1) acc += __shfl_xor(acc, off, 64);
        if (l == 0) q2a[blk * Cc + c] = acc;
    } else {
        const float* W = Ww + (size_t)blk * Cc * Cc;
        const float* gbb = gb + (size_t)blk * Cc;
        for (int j = l; j < Cc; j += 64) acc += W[(size_t)c * Cc + j] * gbb[j];
        for (int off = 32; off > 0; off >>= 1) acc += __shfl_xor(acc, off, 64);
        if (l == 0) cca[blk * Cc + c] = acc + Wb[(size_t)blk * Cc + c];
    }
}

// ---------------- bbox head ----------------
__global__ void bbox_kernel(const float* __restrict__ pos, const float* __restrict__ w,
                            const float* __restrict__ bias, const float* __restrict__ s,
                            const float* __restrict__ t, float* __restrict__ V) {
    __shared__ float ws[32][4];
    int tid = threadIdx.x;
    if (tid < 128) ws[tid >> 2][tid & 3] = w[tid];
    __syncthreads();
    int r = blockIdx.x * 8 + (tid >> 5);
    int o = tid & 31;
    int n = r % Nn;
    float sc = s[n], sh = t[n];
    float p0 = pos[(size_t)r * 4 + 0] * sc + sh;
    float p1 = pos[(size_t)r * 4 + 1] * sc + sh;
    float p2 = pos[(size_t)r * 4 + 2] * sc + sh;
    float p3 = pos[(size_t)r * 4 + 3] * sc + sh;
    float acc = bias[o] + p0 * ws[o][0] + p1 * ws[o][1] + p2 * ws[o][2] + p3 * ws[o][3];
    acc = acc > 0.f ? acc : expm1f(acc);
    V[(size_t)r * Cc + 480 + o] = acc;
}

// ================ fused attention: R = T V^T + ct -> softmax -> Wy = A Z + cc ================
// 1D grid 512, XCD-swizzled. Writes Wy into TZ[:,0:512] (over T), BN partials into part.
__global__ __launch_bounds__(256) void attn_fused_kernel(
    float* __restrict__ TZ, const float* __restrict__ V,
    const float* __restrict__ q2, const float* __restrict__ cc,
    float* __restrict__ part) {
    __shared__ float smem[11904];
    float* Ts = smem;            // [50][36]
    float* Vs = smem + 1800;     // [100][36]
    float* A_lds = smem;         // [50][105] overlay after R compute
    float* ct_lds = smem + 5400; // [100]
    float* Zs = smem + 5504;     // [25][256]; reused for softmax partials + BN sums

    int bid = blockIdx.x;
    int xcd = bid & 7;
    int l = bid >> 3;
    int b = xcd * 32 + (l >> 1);
    int rh = l & 1;
    int row0 = b * Nn + rh * 50;
    int tid = threadIdx.x;
    int lane = tid & 63, wave = tid >> 6;
    int tx = tid & 31, ty = tid >> 5;  // ty 0..7

    // ---- ct[r] = V[b,r,:] . q2 ----
    {
        int r = tid >> 1, h = tid & 1;
        float cacc = 0.f;
        if (r < Nn) {
            const float4* vp = (const float4*)(V + (size_t)(b * Nn + r) * 512);
            const float4* qp = (const float4*)q2;
            for (int c4 = h; c4 < 128; c4 += 2) {
                float4 f = vp[c4], q = qp[c4];
                cacc += f.x * q.x + f.y * q.y + f.z * q.z + f.w * q.w;
            }
        }
        cacc += __shfl_xor(cacc, 1, 64);
        if (r < Nn && h == 0) ct_lds[r] = cacc;
    }

    // ---- R = T V^T ----
    float acc[7][4];
#pragma unroll
    for (int i = 0; i < 7; i++)
#pragma unroll
        for (int j = 0; j < 4; j++) acc[i][j] = 0.f;

    for (int kt = 0; kt < 16; kt++) {
        __syncthreads();
        for (int i = tid; i < 1200; i += 256) {
            if (i < 400) {
                int r = i >> 3, q = i & 7;
                float4 f = *(const float4*)(TZ + (size_t)(row0 + r) * 1024 + kt * 32 + q * 4);
                *(float4*)&Ts[r * 36 + q * 4] = f;
            } else {
                int ii = i - 400;
                int r = ii >> 3, q = ii & 7;
                float4 f = *(const float4*)(V + (size_t)(b * Nn + r) * 512 + kt * 32 + q * 4);
                *(float4*)&Vs[r * 36 + q * 4] = f;
            }
        }
        __syncthreads();
#pragma unroll
        for (int q = 0; q < 8; q++) {
            float4 av[7];
#pragma unroll
            for (int i = 0; i < 7; i++)
                av[i] = *(const float4*)&Ts[(ty * 7 + i) * 36 + q * 4];
            float4 bv[4];
#pragma unroll
            for (int j = 0; j < 4; j++)
                bv[j] = *(const float4*)&Vs[(tx + 32 * j) * 36 + q * 4];
#pragma unroll
            for (int kk = 0; kk < 4; kk++) {
#pragma unroll
                for (int i = 0; i < 7; i++) {
                    float a = ((const float*)&av[i])[kk];
#pragma unroll
                    for (int j = 0; j < 4; j++)
                        acc[i][j] = fmaf(a, ((const float*)&bv[j])[kk], acc[i][j]);
                }
            }
        }
    }
    __syncthreads();

    // ---- A_lds = R + ct ----
    float ctv[4];
#pragma unroll
    for (int j = 0; j < 4; j++) {
        int c = tx + 32 * j;
        ctv[j] = (c < Nn) ? ct_lds[c] : 0.f;
    }
#pragma unroll
    for (int i = 0; i < 7; i++) {
        int r = ty * 7 + i;
        if (r >= 50) continue;
#pragma unroll
        for (int j = 0; j < 4; j++) {
            int c = tx + 32 * j;
            if (c < Nn) A_lds[r * 105 + c] = acc[i][j] + ctv[j];
        }
    }
    __syncthreads();

    // ---- parallel softmax: (row, quarter) decomposition, partials in Zs ----
    {
        int r = tid >> 2, q = tid & 3;       // r 0..63, q 0..3
        float* pmax = Zs;                    // [50][4] stride 4
        float* psum = Zs + 256;              // [50][4]
        if (r < 50) {
            const float* row = A_lds + r * 105 + q * 25;
            float mx = row[0];
            for (int m = 1; m < 25; m++) mx = fmaxf(mx, row[m]);
            pmax[r * 4 + q] = mx;
        }
        __syncthreads();
        if (r < 50) {
            float rowmax = fmaxf(fmaxf(pmax[r * 4 + 0], pmax[r * 4 + 1]),
                                 fmaxf(pmax[r * 4 + 2], pmax[r * 4 + 3]));
            float* row = A_lds + r * 105 + q * 25;
            float sm = 0.f;
            for (int m = 0; m < 25; m++) {
                float e = expf(row[m] - rowmax);
                row[m] = e; sm += e;
            }
            psum[r * 4 + q] = sm;
        }
        __syncthreads();
        if (r < 50) {
            float tot = psum[r * 4 + 0] + psum[r * 4 + 1] + psum[r * 4 + 2] + psum[r * 4 + 3];
            float inv = 1.f / tot;
            float* row = A_lds + r * 105 + q * 25;
            for (int m = 0; m < 25; m++) row[m] *= inv;
        }
    }

    // ---- PV: Wy = A @ Z + cc, per 256-col half -> TZ[:,0:512] ----
    int pair = b * 2 + rh;
    for (int ch = 0; ch < 2; ch++) {
        float acc2[7][8];
#pragma unroll
        for (int i = 0; i < 7; i++)
#pragma unroll
            for (int j = 0; j < 8; j++) acc2[i][j] = 0.f;

        for (int kt = 0; kt < 4; kt++) {
            __syncthreads();   // prior Zs users done (softmax scratch / prev BN sums)
            for (int r = wave; r < 25; r += 4) {
                gload_lds16(TZ + (size_t)(b * Nn + kt * 25 + r) * 1024 + 512 + ch * 256 + lane * 4,
                            (char*)&Zs[r * 256]);
            }
            __syncthreads();
#pragma unroll 5
            for (int k2 = 0; k2 < 25; k2++) {
                int k = kt * 25 + k2;
                float av[7];
#pragma unroll
                for (int i = 0; i < 7; i++) av[i] = A_lds[(ty * 7 + i) * 105 + k];
                float zv[8];
#pragma unroll
                for (int j = 0; j < 8; j++) zv[j] = Zs[k2 * 256 + tx + 32 * j];
#pragma unroll
                for (int i = 0; i < 7; i++)
#pragma unroll
                    for (int j = 0; j < 8; j++)
                        acc2[i][j] = fmaf(av[i], zv[j], acc2[i][j]);
            }
        }

        float ccv[8];
#pragma unroll
        for (int j = 0; j < 8; j++) ccv[j] = cc[ch * 256 + tx + 32 * j];
        float psum[8], psq[8];
#pragma unroll
        for (int j = 0; j < 8; j++) { psum[j] = 0.f; psq[j] = 0.f; }
#pragma unroll
        for (int i = 0; i < 7; i++) {
            int r = ty * 7 + i;
            if (r >= 50) continue;
            float* orow = TZ + (size_t)(row0 + r) * 1024 + ch * 256;
#pragma unroll
            for (int j = 0; j < 8; j++) {
                float v = acc2[i][j] + ccv[j];
                orow[tx + 32 * j] = v;
                psum[j] += v; psq[j] += v * v;
            }
        }
        // deterministic BN partial reduction (reuse Zs as sums[8][2][256])
        __syncthreads();
        float* sums = Zs;
#pragma unroll
        for (int j = 0; j < 8; j++) {
            int c = tx + 32 * j;
            sums[ty * 512 + c] = psum[j];
            sums[ty * 512 + 256 + c] = psq[j];
        }
        __syncthreads();
        {
            float ssv = 0.f, sqv = 0.f;
            for (int y = 0; y < 8; y++) {
                ssv += sums[y * 512 + tid];
                sqv += sums[y * 512 + 256 + tid];
            }
            part[(size_t)pair * 1024 + ch * 256 + tid] = ssv;
            part[(size_t)pair * 1024 + 512 + ch * 256 + tid] = sqv;
        }
    }
}

// ---------------- finalize channel-BN from partials: grid 512, block 64 ----------------
__global__ void wy_fin2_kernel(const float* __restrict__ part,
                               const float* __restrict__ g, const float* __restrict__ bb,
                               float* __restrict__ s, float* __restrict__ t) {
    int c = blockIdx.x;
    int l = threadIdx.x; // 64
    float sum = 0.f, sq = 0.f;
    for (int p = l; p < 512; p += 64) {
        sum += part[(size_t)p * 1024 + c];
        sq  += part[(size_t)p * 1024 + 512 + c];
    }
    for (int off = 32; off > 0; off >>= 1) {
        sum += __shfl_xor(sum, off, 64);
        sq  += __shfl_xor(sq, off, 64);
    }
    if (l == 0) {
        float m   = sum / BN_ROWS;
        float var = sq / BN_ROWS - m * m;
        float sc  = g[c] * rsqrtf(var + EPS);
        s[c] = sc;
        t[c] = bb[c] - m * sc;
    }
}

// ---------------- residual: V += Wy*s[c] + t[c] (Wy strided in TZ) ----------------
__global__ void residual_kernel(float* __restrict__ V, const float* __restrict__ Wy, int ldw,
                                const float* __restrict__ s, const float* __restrict__ t) {
    size_t total4 = (size_t)BN_ROWS * Cc / 4;
    for (size_t i4 = (size_t)blockIdx.x * blockDim.x + threadIdx.x; i4 < total4;
         i4 += (size_t)gridDim.x * blockDim.x) {
        int row = (int)(i4 >> 7);
        int c = (int)(i4 & 127) * 4;
        float4 w = *(const float4*)(Wy + (size_t)row * ldw + c);
        float4 sv = *(const float4*)(s + c);
        float4 tv = *(const float4*)(t + c);
        float4 v = *(float4*)(V + (size_t)row * Cc + c);
        v.x += w.x * sv.x + tv.x; v.y += w.y * sv.y + tv.y;
        v.z += w.z * sv.z + tv.z; v.w += w.w * sv.w + tv.w;
        *(float4*)(V + (size_t)row * Cc + c) = v;
    }
}

// ---------------- l2norm over node dim + mean, final residual folded ----------------
__global__ void l2norm_mean_kernel(const float* __restrict__ V, const float* __restrict__ TZwy,
                                   const float* __restrict__ s, const float* __restrict__ t,
                                   float* __restrict__ ALL) {
    int b = blockIdx.x;
    int c = threadIdx.x; // 512
    float sc = s[c], sh = t[c];
    float sum = 0.f, sq = 0.f;
    const float* p = V + (size_t)b * Nn * Cc + c;
    const float* w = TZwy + (size_t)b * Nn * 1024 + c;
    for (int n = 0; n < Nn; n++) {
        float v = p[(size_t)n * Cc] + w[(size_t)n * 1024] * sc + sh;
        sum += v; sq += v * v;
    }
    ALL[(size_t)b * 1536 + 512 + c] = sum / (Nn * sqrtf(sq));
}

// ---------------- final: BN(all_feats) @ ff_w.T + ff_b -> (256,2) ----------------
__global__ void final_kernel(const float* __restrict__ ALL, const float* __restrict__ s,
                             const float* __restrict__ t, const float* __restrict__ w,
                             const float* __restrict__ bias, float* __restrict__ out) {
    int b = blockIdx.x;
    int tid = threadIdx.x; // 256
    float p0 = 0.f, p1 = 0.f;
    for (int k = tid; k < 1536; k += 256) {
        float af = ALL[(size_t)b * 1536 + k] * s[k] + t[k];
        p0 += af * w[k];
        p1 += af * w[1536 + k];
    }
    __shared__ float s0[256], s1[256];
    s0[tid] = p0; s1[tid] = p1;
    __syncthreads();
    for (int off = 128; off > 0; off >>= 1) {
        if (tid < off) { s0[tid] += s0[tid + off]; s1[tid] += s1[tid + off]; }
        __syncthreads();
    }
    if (tid == 0) {
        out[b * 2 + 0] = s0[0] + bias[0];
        out[b * 2 + 1] = s1[0] + bias[1];
    }
}

extern "C" void kernel_launch(void* const* d_in, const int* in_sizes, int n_in,
                              void* d_out, int out_size, void* d_ws, size_t ws_size,
                              hipStream_t stream) {
    const float* img   = (const float*)d_in[0];
    const float* txt   = (const float*)d_in[1];
    const float* node  = (const float*)d_in[2];
    const float* pos   = (const float*)d_in[3];
    const float* swinbn_g = (const float*)d_in[4];
    const float* swinbn_b = (const float*)d_in[5];
    const float* swinfc_w = (const float*)d_in[6];
    const float* swinfc_b = (const float*)d_in[7];
    const float* bntext_g = (const float*)d_in[8];
    const float* bntext_b = (const float*)d_in[9];
    const float* fctext_w = (const float*)d_in[10];
    const float* fctext_b = (const float*)d_in[11];
    const float* bngat_g  = (const float*)d_in[12];
    const float* bngat_b  = (const float*)d_in[13];
    const float* fcgat_w  = (const float*)d_in[14];
    const float* fcgat_b  = (const float*)d_in[15];
    const float* bnbbox_g = (const float*)d_in[16];
    const float* bnbbox_b = (const float*)d_in[17];
    const float* fcbbox_w = (const float*)d_in[18];
    const float* fcbbox_b = (const float*)d_in[19];
    const float* gcn_theta_w = (const float*)d_in[20];
    const float* gcn_theta_b = (const float*)d_in[21];
    const float* gcn_phi_w   = (const float*)d_in[22];
    const float* gcn_phi_b   = (const float*)d_in[23];
    const float* gcn_g_w     = (const float*)d_in[24];
    const float* gcn_g_b     = (const float*)d_in[25];
    const float* gcn_W_w     = (const float*)d_in[26];
    const float* gcn_W_b     = (const float*)d_in[27];
    const float* gcn_bn_g    = (const float*)d_in[28];
    const float* gcn_bn_b    = (const float*)d_in[29];
    const float* ffbn_g = (const float*)d_in[30];
    const float* ffbn_b = (const float*)d_in[31];
    const float* ff_w   = (const float*)d_in[32];
    const float* ff_b   = (const float*)d_in[33];

    float* ws = (float*)d_ws;
    const size_t VN = (size_t)BN_ROWS * Cc;          // 13,107,200
    const size_t CC2 = (size_t)Cc * Cc;              // 262,144
    float* V       = ws;                              // VN
    float* TZ      = V + VN;                          // 2*VN (25600 x 1024)
    float* Mw_all  = TZ + 2 * VN;                     // 8*CC2
    float* WGT_all = Mw_all + 8 * CC2;                // 8*CC2
    float* WT      = WGT_all + 8 * CC2;               // 393,216
    float* ALL     = WT + 393216;                     // 393,216
    float* part    = ALL + (size_t)Bsz * 1536;        // 524,288 (also npart)
    float* q2_all  = part + 524288;                   // 8 x 512
    float* cc_all  = q2_all + 4096;                   // 8 x 512
    float* st      = cc_all + 4096;
    float* s_img = st;            float* t_img = s_img + 1024;
    float* s_txt = t_img + 1024;  float* t_txt = s_txt + 768;
    float* s_nd  = t_txt + 768;   float* t_nd  = s_nd + 128;
    float* s_bb  = t_nd + 128;    float* t_bb  = s_bb + 128;
    float* s_g   = t_bb + 128;    float* t_g   = s_g + 512;
    float* s_ff  = t_g + 512;     float* t_ff  = s_ff + 1536;
    float* pb    = t_ff + 1536;   // 512 padded fcgat bias

    dim3 blk(256);

    // input BN stats
    colstats_kernel<<<1024, 256, 0, stream>>>(img, 256, 1024, swinbn_g, swinbn_b, s_img, t_img);
    colstats_kernel<<<768, 256, 0, stream>>>(txt, 256, 768, bntext_g, bntext_b, s_txt, t_txt);
    chstats_part_kernel<<<dim3(100, 16, 1), 256, 0, stream>>>(node, part);
    chstats_fin_kernel<<<1, 128, 0, stream>>>(part, bngat_g, bngat_b, s_nd, t_nd);
    chstats_kernel<<<100, 256, 0, stream>>>(pos, 4, bnbbox_g, bnbbox_b, s_bb, t_bb);

    // heads
    gemm_kernel<1, true, true><<<dim3(4, 8, 1), blk, 0, stream>>>(
        img, swinfc_w, swinfc_b, s_img, t_img, 256, 512, 1024, 1024, 1024, 0,
        ALL, 1536, 0);
    gemm_kernel<1, true, true><<<dim3(4, 8, 1), blk, 0, stream>>>(
        txt, fctext_w, fctext_b, s_txt, t_txt, 256, 512, 768, 768, 768, 0,
        ALL, 1536, 1024);
    transpose_w_kernel<<<dim3(24, 16, 1), blk, 0, stream>>>(fcgat_w, fcgat_b, WT, pb);
    gemm128_kernel<2, true, false, 32, 2><<<800, blk, 0, stream>>>(
        node, WT, nullptr, 4, pb, s_nd, t_nd,
        25600, 512, 768, 768, 512, 100, V, 512, 0);
    bbox_kernel<<<3200, 256, 0, stream>>>(pos, fcbbox_w, fcbbox_b, s_bb, t_bb, V);

    // all weight-side composes upfront
    compose_kernel<<<dim3(16, 8, 16), blk, 0, stream>>>(
        gcn_theta_w, gcn_phi_w, gcn_g_w, gcn_W_w, Mw_all, WGT_all);
    qc_kernel<<<dim3(512, 16, 1), 64, 0, stream>>>(
        gcn_phi_w, gcn_theta_b, gcn_W_w, gcn_g_b, gcn_W_b, q2_all, cc_all);

    // 8 GCN blocks: wide-tile gemm -> fused attention -> BN finalize -> residual
    for (int i = 0; i < 8; i++) {
        gemm256_kernel<32><<<800, blk, 0, stream>>>(
            V, Mw_all + (size_t)i * CC2, WGT_all + (size_t)i * CC2, 2,
            25600, 512, 512, 512, TZ, 1024);

        attn_fused_kernel<<<512, blk, 0, stream>>>(
            TZ, V, q2_all + (size_t)i * Cc, cc_all + (size_t)i * Cc, part);

        wy_fin2_kernel<<<512, 64, 0, stream>>>(part, gcn_bn_g + (size_t)i * Cc,
                                               gcn_bn_b + (size_t)i * Cc, s_g, t_g);

        if (i < 7)
            residual_kernel<<<4096, 256, 0, stream>>>(V, TZ, 1024, s_g, t_g);
    }

    // l2norm over node dim + mean (last residual folded here)
    l2norm_mean_kernel<<<256, 512, 0, stream>>>(V, TZ, s_g, t_g, ALL);
    // final BN + tiny FC
    colstats_kernel<<<1536, 256, 0, stream>>>(ALL, 256, 1536, ffbn_g, ffbn_b, s_ff, t_ff);
    final_kernel<<<256, 256, 0, stream>>>(ALL, s_ff, t_ff, ff_w, ff_b, (float*)d_out);
}

// Round 12
// 4619.815 us; speedup vs baseline: 1.0484x; 1.0484x over previous
//
#include <hip/hip_runtime.h>
#include <cstddef>

#define EPS 1e-5f

constexpr int Bsz = 256;
constexpr int Nn  = 100;
constexpr int Cc  = 512;
constexpr int BN_ROWS = Bsz * Nn; // 25600

__device__ __forceinline__ void gload_lds16(const void* g, void* l) {
    __builtin_amdgcn_global_load_lds(
        (const __attribute__((address_space(1))) void*)g,
        (__attribute__((address_space(3))) void*)l, 16, 0, 0);
}

// ---------------- per-column stats over M rows (M <= 256), grid = Ccols ----------------
__global__ void colstats_kernel(const float* __restrict__ x, int M, int Ccols,
                                const float* __restrict__ g, const float* __restrict__ bb,
                                float* __restrict__ s, float* __restrict__ t) {
    int c = blockIdx.x;
    int r = threadIdx.x;
    float v = (r < M) ? x[(size_t)r * Ccols + c] : 0.f;
    __shared__ float ssum[256], ssq[256];
    ssum[r] = v; ssq[r] = v * v;
    __syncthreads();
    for (int off = 128; off > 0; off >>= 1) {
        if (r < off) { ssum[r] += ssum[r + off]; ssq[r] += ssq[r + off]; }
        __syncthreads();
    }
    if (r == 0) {
        float m   = ssum[0] / M;
        float var = ssq[0] / M - m * m;
        float sc  = g[c] * rsqrtf(var + EPS);
        s[c] = sc;
        t[c] = bb[c] - m * sc;
    }
}

// ---------------- small per-node-channel stats (pos: D=4), grid = Nn ----------------
__global__ void chstats_kernel(const float* __restrict__ x, int D,
                               const float* __restrict__ g, const float* __restrict__ bb,
                               float* __restrict__ s, float* __restrict__ t) {
    int n = blockIdx.x;
    int tid = threadIdx.x;
    int total = Bsz * D;
    float sum = 0.f, sq = 0.f;
    for (int idx = tid; idx < total; idx += blockDim.x) {
        int b = idx / D, d = idx - b * D;
        float v = x[((size_t)b * Nn + n) * D + d];
        sum += v; sq += v * v;
    }
    __shared__ float ssum[256], ssq[256];
    ssum[tid] = sum; ssq[tid] = sq;
    __syncthreads();
    for (int off = 128; off > 0; off >>= 1) {
        if (tid < off) { ssum[tid] += ssum[tid + off]; ssq[tid] += ssq[tid + off]; }
        __syncthreads();
    }
    if (tid == 0) {
        float m   = ssum[0] / total;
        float var = ssq[0] / total - m * m;
        float sc  = g[n] * rsqrtf(var + EPS);
        s[n] = sc;
        t[n] = bb[n] - m * sc;
    }
}

// ---------------- node-emb channel stats, two-stage: grid (100, 16) ----------------
__global__ void chstats_part_kernel(const float* __restrict__ x, float* __restrict__ npart) {
    int n = blockIdx.x, chunk = blockIdx.y;
    int tid = threadIdx.x;
    float sum = 0.f, sq = 0.f;
    for (int i = tid; i < 3072; i += 256) {
        int rrow = i / 192;
        int q = i - rrow * 192;
        float4 f = *(const float4*)(x + ((size_t)(chunk * 16 + rrow) * Nn + n) * 768 + q * 4);
        sum += f.x + f.y + f.z + f.w;
        sq  += f.x * f.x + f.y * f.y + f.z * f.z + f.w * f.w;
    }
    __shared__ float ss[256], s2[256];
    ss[tid] = sum; s2[tid] = sq;
    __syncthreads();
    for (int off = 128; off > 0; off >>= 1) {
        if (tid < off) { ss[tid] += ss[tid + off]; s2[tid] += s2[tid + off]; }
        __syncthreads();
    }
    if (tid == 0) {
        npart[chunk * 200 + n] = ss[0];
        npart[chunk * 200 + 100 + n] = s2[0];
    }
}

__global__ void chstats_fin_kernel(const float* __restrict__ npart,
                                   const float* __restrict__ g, const float* __restrict__ bb,
                                   float* __restrict__ s, float* __restrict__ t) {
    int n = threadIdx.x;
    if (n >= 100) return;
    float sum = 0.f, sq = 0.f;
    for (int c = 0; c < 16; c++) {
        sum += npart[c * 200 + n];
        sq  += npart[c * 200 + 100 + n];
    }
    const float total = 256.f * 768.f;
    float m   = sum / total;
    float var = sq / total - m * m;
    float sc  = g[n] * rsqrtf(var + EPS);
    s[n] = sc;
    t[n] = bb[n] - m * sc;
}

// ---------------- transpose fcgat weights (480x768 -> 768x512 zero-padded) ----------------
__global__ void transpose_w_kernel(const float* __restrict__ w, const float* __restrict__ bias,
                                   float* __restrict__ WT, float* __restrict__ pb) {
    __shared__ float tile[32][33];
    int kb = blockIdx.x * 32, nb = blockIdx.y * 32;
    int tx = threadIdx.x & 31, ty = threadIdx.x >> 5; // 32x8
#pragma unroll
    for (int i = 0; i < 4; i++) {
        int n = nb + ty + i * 8;
        tile[ty + i * 8][tx] = (n < 480) ? w[(size_t)n * 768 + kb + tx] : 0.f;
    }
    __syncthreads();
#pragma unroll
    for (int i = 0; i < 4; i++) {
        int k = kb + ty + i * 8;
        WT[(size_t)k * 512 + nb + tx] = tile[tx][ty + i * 8];
    }
    if (blockIdx.x == 0 && threadIdx.x < 32) {
        int n = nb + threadIdx.x;
        pb[n] = (n < 480) ? bias[n] : 0.f;
    }
}

// ========== single-buffer 128x128 fp32 GEMM, 8x8 micro-tile, K-step KS ==========
// 1D grid with XCD-bijective swizzle. grid = nbm * (1<<BYSHIFT), nbm%8==0.
// NORM: 0 none, 2 per-row (s[m % mod]).
// TB=true : B is (N x K) row-major (reg-staged, N-guarded)
// TB=false: B is (K x N) row-major (global_load_lds staged)
template <int NORM, bool ELU, bool TB, int KS, int BYSHIFT>
__global__ __launch_bounds__(256) void gemm128_kernel(
    const float* __restrict__ A, const float* __restrict__ B0,
    const float* __restrict__ B1, int nsplit,
    const float* __restrict__ bias,
    const float* __restrict__ s, const float* __restrict__ t,
    int M, int N, int K, int lda, int ldb, int mod,
    float* __restrict__ C, int ldc, int c_off) {
    constexpr int BS = TB ? 132 : 128;
    __shared__ float As[KS * 132];
    __shared__ float Bs[KS * BS];

    int bid = blockIdx.x;
    int xcd = bid & 7;
    int l = bid >> 3;
    int by = l & ((1 << BYSHIFT) - 1);
    int bmi = l >> BYSHIFT;
    int bm_per_xcd = (int)(gridDim.x >> (3 + BYSHIFT));
    int bm = (xcd * bm_per_xcd + bmi) * 128;

    const float* B = (by < nsplit) ? B0 : B1;
    int bn = (by < nsplit ? by : by - nsplit) * 128;
    int outcol0 = c_off + by * 128;

    int tid = threadIdx.x;
    int lane = tid & 63, wave = tid >> 6;
    int tx = tid & 15, ty = tid >> 4;

    float acc[8][8] = {};

    for (int k0 = 0; k0 < K; k0 += KS) {
        // ---- stage B async first (hides under A reg work) ----
        if constexpr (!TB) {
#pragma unroll
            for (int i = 0; i < KS / 8; i++) {
                int r = i * 8 + wave * 2 + (lane >> 5);
                gload_lds16(B + (size_t)(k0 + r) * ldb + bn + (lane & 31) * 4,
                            (char*)&Bs[r * BS]);
            }
        }
        // ---- stage A (reg -> LDS transpose) ----
#pragma unroll
        for (int i = 0; i < KS / 8; i++) {
            int id = tid + i * 256;
            int row = id / (KS / 4), q = id % (KS / 4);
            int gr = bm + row;
            float4 f = *(const float4*)(A + (size_t)gr * lda + k0 + q * 4);
            if constexpr (NORM == 2) {
                int n_ = gr % mod; float sc = s[n_], sh = t[n_];
                f.x = f.x * sc + sh; f.y = f.y * sc + sh;
                f.z = f.z * sc + sh; f.w = f.w * sc + sh;
            }
            As[(q * 4 + 0) * 132 + row] = f.x;
            As[(q * 4 + 1) * 132 + row] = f.y;
            As[(q * 4 + 2) * 132 + row] = f.z;
            As[(q * 4 + 3) * 132 + row] = f.w;
        }
        if constexpr (TB) {
#pragma unroll
            for (int i = 0; i < KS / 8; i++) {
                int id = tid + i * 256;
                int row = id / (KS / 4), q = id % (KS / 4);
                int gn = bn + row;
                float4 f = make_float4(0.f, 0.f, 0.f, 0.f);
                if (gn < N) f = *(const float4*)(B + (size_t)gn * ldb + k0 + q * 4);
                Bs[(q * 4 + 0) * BS + row] = f.x;
                Bs[(q * 4 + 1) * BS + row] = f.y;
                Bs[(q * 4 + 2) * BS + row] = f.z;
                Bs[(q * 4 + 3) * BS + row] = f.w;
            }
        }
        __syncthreads();
#pragma unroll 16
        for (int kk = 0; kk < KS; kk++) {
            float4 a0 = *(const float4*)&As[kk * 132 + ty * 4];
            float4 a1 = *(const float4*)&As[kk * 132 + ty * 4 + 64];
            float4 b0 = *(const float4*)&Bs[kk * BS + tx * 4];
            float4 b1 = *(const float4*)&Bs[kk * BS + tx * 4 + 64];
            float av[8] = {a0.x, a0.y, a0.z, a0.w, a1.x, a1.y, a1.z, a1.w};
            float bv[8] = {b0.x, b0.y, b0.z, b0.w, b1.x, b1.y, b1.z, b1.w};
#pragma unroll
            for (int i = 0; i < 8; i++)
#pragma unroll
                for (int j = 0; j < 8; j++)
                    acc[i][j] = fmaf(av[i], bv[j], acc[i][j]);
        }
        __syncthreads();
    }

#pragma unroll
    for (int i = 0; i < 8; i++) {
        int r = ty * 4 + (i & 3) + ((i & 4) ? 64 : 0);
        int gr = bm + r;
        if (gr >= M) continue;
        float* crow = C + (size_t)gr * ldc + outcol0;
#pragma unroll
        for (int h = 0; h < 2; h++) {
            int cl = tx * 4 + h * 64;
            int gcol = bn + cl;
            if constexpr (TB) { if (gcol >= N) continue; }
            float4 o;
            o.x = acc[i][h * 4 + 0]; o.y = acc[i][h * 4 + 1];
            o.z = acc[i][h * 4 + 2]; o.w = acc[i][h * 4 + 3];
            if (bias) {
                o.x += bias[gcol]; o.y += bias[gcol + 1];
                o.z += bias[gcol + 2]; o.w += bias[gcol + 3];
            }
            if constexpr (ELU) {
                o.x = o.x > 0.f ? o.x : expm1f(o.x);
                o.y = o.y > 0.f ? o.y : expm1f(o.y);
                o.z = o.z > 0.f ? o.z : expm1f(o.z);
                o.w = o.w > 0.f ? o.w : expm1f(o.w);
            }
            *(float4*)(crow + cl) = o;
        }
    }
}

// ---------------- generic 64x64 tiled GEMM (small heads) ----------------
template <int NORM, bool ELU, bool TB>
__global__ void gemm_kernel(const float* __restrict__ A, const float* __restrict__ B,
                            const float* __restrict__ bias,
                            const float* __restrict__ s, const float* __restrict__ t,
                            int M, int N, int K, int lda, int ldb, int mod,
                            float* __restrict__ Cout, int ldc, int c_off) {
    __shared__ float As[16][65];
    __shared__ float Bs[16][65];

    int bm = blockIdx.x * 64, bn = blockIdx.y * 64;
    int tid = threadIdx.x;
    int tm = (tid >> 4) << 2;
    int tn = (tid & 15) << 2;
    float acc[4][4] = {};

    for (int k0 = 0; k0 < K; k0 += 16) {
#pragma unroll
        for (int i = 0; i < 4; i++) {
            int idx = tid + i * 256;
            {
                int rr = idx >> 4, kk = idx & 15;
                int gr = bm + rr, gk = k0 + kk;
                float av = 0.f;
                if (gr < M && gk < K) {
                    av = A[(size_t)gr * lda + gk];
                    if constexpr (NORM == 1) av = av * s[gk] + t[gk];
                    else if constexpr (NORM == 2) { int n_ = gr % mod; av = av * s[n_] + t[n_]; }
                }
                As[kk][rr] = av;
            }
            if constexpr (TB) {
                int nn = idx >> 4, kk = idx & 15;
                int gn = bn + nn, gk = k0 + kk;
                Bs[kk][nn] = (gn < N && gk < K) ? B[(size_t)gn * ldb + gk] : 0.f;
            } else {
                int kk = idx >> 6, nn = idx & 63;
                int gn = bn + nn, gk = k0 + kk;
                Bs[kk][nn] = (gn < N && gk < K) ? B[(size_t)gk * ldb + gn] : 0.f;
            }
        }
        __syncthreads();
#pragma unroll
        for (int kk = 0; kk < 16; kk++) {
            float a0[4], b0[4];
#pragma unroll
            for (int i = 0; i < 4; i++) a0[i] = As[kk][tm + i];
#pragma unroll
            for (int j = 0; j < 4; j++) b0[j] = Bs[kk][tn + j];
#pragma unroll
            for (int i = 0; i < 4; i++)
#pragma unroll
                for (int j = 0; j < 4; j++)
                    acc[i][j] = fmaf(a0[i], b0[j], acc[i][j]);
        }
        __syncthreads();
    }

#pragma unroll
    for (int i = 0; i < 4; i++) {
        int gr = bm + tm + i;
        if (gr >= M) continue;
#pragma unroll
        for (int j = 0; j < 4; j++) {
            int gn = bn + tn + j;
            if (gn >= N) continue;
            float v = acc[i][j] + (bias ? bias[gn] : 0.f);
            if constexpr (ELU) v = v > 0.f ? v : expm1f(v);
            Cout[(size_t)gr * ldc + c_off + gn] = v;
        }
    }
}

// ---------------- compose (all 8 GCN blocks): z = blk*2 + which ----------------
__global__ __launch_bounds__(256) void compose_kernel(
    const float* __restrict__ thw, const float* __restrict__ phw,
    const float* __restrict__ gw, const float* __restrict__ Ww,
    float* __restrict__ Mw_all, float* __restrict__ WGT_all) {
    __shared__ float As[32][33];
    __shared__ float Bs[32][68];
    int blk = blockIdx.z >> 1;
    int z = blockIdx.z & 1;
    size_t woff = (size_t)blk * Cc * Cc;
    const float* A = (z ? gw : thw) + woff;
    const float* ph = phw + woff;
    const float* W = Ww + woff;
    int bm = blockIdx.x * 32, bn = blockIdx.y * 64;
    int tid = threadIdx.x;
    int tm = (tid >> 4) * 2, tn = (tid & 15) * 4;
    float acc[2][4] = {};

    for (int k0 = 0; k0 < Cc; k0 += 32) {
#pragma unroll
        for (int i = 0; i < 4; i++) {
            int id = tid + i * 256;
            int kk = id >> 5, m = id & 31;
            As[kk][m] = A[(size_t)(k0 + kk) * Cc + bm + m];
        }
#pragma unroll
        for (int i = 0; i < 8; i++) {
            int id = tid + i * 256;
            if (z == 0) {
                int kk = id >> 6, n = id & 63;
                Bs[kk][n] = ph[(size_t)(k0 + kk) * Cc + bn + n];
            } else {
                int n = id >> 5, kk = id & 31;
                Bs[kk][n] = W[(size_t)(bn + n) * Cc + k0 + kk];
            }
        }
        __syncthreads();
#pragma unroll
        for (int kk = 0; kk < 32; kk++) {
            float a0 = As[kk][tm], a1 = As[kk][tm + 1];
            float4 b4 = *(const float4*)&Bs[kk][tn];
            acc[0][0] = fmaf(a0, b4.x, acc[0][0]);
            acc[0][1] = fmaf(a0, b4.y, acc[0][1]);
            acc[0][2] = fmaf(a0, b4.z, acc[0][2]);
            acc[0][3] = fmaf(a0, b4.w, acc[0][3]);
            acc[1][0] = fmaf(a1, b4.x, acc[1][0]);
            acc[1][1] = fmaf(a1, b4.y, acc[1][1]);
            acc[1][2] = fmaf(a1, b4.z, acc[1][2]);
            acc[1][3] = fmaf(a1, b4.w, acc[1][3]);
        }
        __syncthreads();
    }
    float* out = (z ? WGT_all : Mw_all) + woff;
    *(float4*)&out[(size_t)(bm + tm) * Cc + bn + tn] =
        make_float4(acc[0][0], acc[0][1], acc[0][2], acc[0][3]);
    *(float4*)&out[(size_t)(bm + tm + 1) * Cc + bn + tn] =
        make_float4(acc[1][0], acc[1][1], acc[1][2], acc[1][3]);
}

// ---------------- q2/cconst for all blocks: grid (512, 16) ----------------
__global__ void qc_kernel(const float* __restrict__ phw, const float* __restrict__ thb,
                          const float* __restrict__ Ww, const float* __restrict__ gb,
                          const float* __restrict__ Wb,
                          float* __restrict__ q2a, float* __restrict__ cca) {
    int blk = blockIdx.y >> 1;
    int type = blockIdx.y & 1;
    int c = blockIdx.x;
    int l = threadIdx.x; // 64
    float acc = 0.f;
    if (type == 0) {
        const float* phi = phw + (size_t)blk * Cc * Cc;
        const float* tb = thb + (size_t)blk * Cc;
        for (int j = l; j < Cc; j += 64) acc += phi[(size_t)j * Cc + c] * tb[j];
        for (int off = 32; off > 0; off >>= 1) acc += __shfl_xor(acc, off, 64);
        if (l == 0) q2a[blk * Cc + c] = acc;
    } else {
        const float* W = Ww + (size_t)blk * Cc * Cc;
        const float* gbb = gb + (size_t)blk * Cc;
        for (int j = l; j < Cc; j += 64) acc += W[(size_t)c * Cc + j] * gbb[j];
        for (int off = 32; off > 0; off >>= 1) acc += __shfl_xor(acc, off, 64);
        if (l == 0) cca[blk * Cc + c] = acc + Wb[(size_t)blk * Cc + c];
    }
}

// ---------------- bbox head ----------------
__global__ void bbox_kernel(const float* __restrict__ pos, const float* __restrict__ w,
                            const float* __restrict__ bias, const float* __restrict__ s,
                            const float* __restrict__ t, float* __restrict__ V) {
    __shared__ float ws[32][4];
    int tid = threadIdx.x;
    if (tid < 128) ws[tid >> 2][tid & 3] = w[tid];
    __syncthreads();
    int r = blockIdx.x * 8 + (tid >> 5);
    int o = tid & 31;
    int n = r % Nn;
    float sc = s[n], sh = t[n];
    float p0 = pos[(size_t)r * 4 + 0] * sc + sh;
    float p1 = pos[(size_t)r * 4 + 1] * sc + sh;
    float p2 = pos[(size_t)r * 4 + 2] * sc + sh;
    float p3 = pos[(size_t)r * 4 + 3] * sc + sh;
    float acc = bias[o] + p0 * ws[o][0] + p1 * ws[o][1] + p2 * ws[o][2] + p3 * ws[o][3];
    acc = acc > 0.f ? acc : expm1f(acc);
    V[(size_t)r * Cc + 480 + o] = acc;
}

// ================ fused attention: R = T V^T + ct -> softmax -> Wy = A Z + cc ================
// 1D grid 512, XCD-swizzled. A_lds stride 108 (16B-aligned float4-over-k reads in PV).
// PV: k-chunks of 20; av via ds_read_b128 over k; zv via 2x ds_read_b128 (cols tx*4, tx*4+128).
__global__ __launch_bounds__(256) void attn_fused_kernel(
    float* __restrict__ TZ, const float* __restrict__ V,
    const float* __restrict__ q2, const float* __restrict__ cc,
    float* __restrict__ part) {
    __shared__ float smem[11904];
    float* Ts = smem;            // [50][36]
    float* Vs = smem + 1800;     // [100][36]
    float* A_lds = smem;         // [50][108] overlay after R compute (5400 floats)
    float* ct_lds = smem + 5400; // [100]
    float* Zs = smem + 5504;     // [20][256] = 5120; reused for softmax partials + BN sums

    int bid = blockIdx.x;
    int xcd = bid & 7;
    int l = bid >> 3;
    int b = xcd * 32 + (l >> 1);
    int rh = l & 1;
    int row0 = b * Nn + rh * 50;
    int tid = threadIdx.x;
    int lane = tid & 63, wave = tid >> 6;
    int tx = tid & 31, ty = tid >> 5;  // ty 0..7

    // ---- ct[r] = V[b,r,:] . q2 ----
    {
        int r = tid >> 1, h = tid & 1;
        float cacc = 0.f;
        if (r < Nn) {
            const float4* vp = (const float4*)(V + (size_t)(b * Nn + r) * 512);
            const float4* qp = (const float4*)q2;
            for (int c4 = h; c4 < 128; c4 += 2) {
                float4 f = vp[c4], q = qp[c4];
                cacc += f.x * q.x + f.y * q.y + f.z * q.z + f.w * q.w;
            }
        }
        cacc += __shfl_xor(cacc, 1, 64);
        if (r < Nn && h == 0) ct_lds[r] = cacc;
    }

    // ---- R = T V^T ----
    float acc[7][4];
#pragma unroll
    for (int i = 0; i < 7; i++)
#pragma unroll
        for (int j = 0; j < 4; j++) acc[i][j] = 0.f;

    for (int kt = 0; kt < 16; kt++) {
        __syncthreads();
        for (int i = tid; i < 1200; i += 256) {
            if (i < 400) {
                int r = i >> 3, q = i & 7;
                float4 f = *(const float4*)(TZ + (size_t)(row0 + r) * 1024 + kt * 32 + q * 4);
                *(float4*)&Ts[r * 36 + q * 4] = f;
            } else {
                int ii = i - 400;
                int r = ii >> 3, q = ii & 7;
                float4 f = *(const float4*)(V + (size_t)(b * Nn + r) * 512 + kt * 32 + q * 4);
                *(float4*)&Vs[r * 36 + q * 4] = f;
            }
        }
        __syncthreads();
#pragma unroll
        for (int q = 0; q < 8; q++) {
            float4 av[7];
#pragma unroll
            for (int i = 0; i < 7; i++)
                av[i] = *(const float4*)&Ts[(ty * 7 + i) * 36 + q * 4];
            float4 bv[4];
#pragma unroll
            for (int j = 0; j < 4; j++)
                bv[j] = *(const float4*)&Vs[(tx + 32 * j) * 36 + q * 4];
#pragma unroll
            for (int kk = 0; kk < 4; kk++) {
#pragma unroll
                for (int i = 0; i < 7; i++) {
                    float a = ((const float*)&av[i])[kk];
#pragma unroll
                    for (int j = 0; j < 4; j++)
                        acc[i][j] = fmaf(a, ((const float*)&bv[j])[kk], acc[i][j]);
                }
            }
        }
    }
    __syncthreads();

    // ---- A_lds = R + ct (stride 108) ----
    float ctv[4];
#pragma unroll
    for (int j = 0; j < 4; j++) {
        int c = tx + 32 * j;
        ctv[j] = (c < Nn) ? ct_lds[c] : 0.f;
    }
#pragma unroll
    for (int i = 0; i < 7; i++) {
        int r = ty * 7 + i;
        if (r >= 50) continue;
#pragma unroll
        for (int j = 0; j < 4; j++) {
            int c = tx + 32 * j;
            if (c < Nn) A_lds[r * 108 + c] = acc[i][j] + ctv[j];
        }
    }
    __syncthreads();

    // ---- parallel softmax: (row, quarter) decomposition, partials in Zs ----
    {
        int r = tid >> 2, q = tid & 3;       // r 0..63, q 0..3
        float* pmax = Zs;                    // [50][4]
        float* psum = Zs + 256;              // [50][4]
        if (r < 50) {
            const float* row = A_lds + r * 108 + q * 25;
            float mx = row[0];
            for (int m = 1; m < 25; m++) mx = fmaxf(mx, row[m]);
            pmax[r * 4 + q] = mx;
        }
        __syncthreads();
        if (r < 50) {
            float rowmax = fmaxf(fmaxf(pmax[r * 4 + 0], pmax[r * 4 + 1]),
                                 fmaxf(pmax[r * 4 + 2], pmax[r * 4 + 3]));
            float* row = A_lds + r * 108 + q * 25;
            float sm = 0.f;
            for (int m = 0; m < 25; m++) {
                float e = expf(row[m] - rowmax);
                row[m] = e; sm += e;
            }
            psum[r * 4 + q] = sm;
        }
        __syncthreads();
        if (r < 50) {
            float tot = psum[r * 4 + 0] + psum[r * 4 + 1] + psum[r * 4 + 2] + psum[r * 4 + 3];
            float inv = 1.f / tot;
            float* row = A_lds + r * 108 + q * 25;
            for (int m = 0; m < 25; m++) row[m] *= inv;
        }
    }

    // ---- PV: Wy = A @ Z + cc, per 256-col half -> TZ[:,0:512] ----
    // cols per thread: c = tx*4 + j (j<4) and c = tx*4 + 128 + (j-4) (j>=4)
    int pair = b * 2 + rh;
    for (int ch = 0; ch < 2; ch++) {
        float acc2[7][8];
#pragma unroll
        for (int i = 0; i < 7; i++)
#pragma unroll
            for (int j = 0; j < 8; j++) acc2[i][j] = 0.f;

        for (int kt = 0; kt < 5; kt++) {   // 5 x 20 k's
            __syncthreads();   // prior Zs users done (softmax scratch / prev chunk)
            for (int r = wave; r < 20; r += 4) {
                gload_lds16(TZ + (size_t)(b * Nn + kt * 20 + r) * 1024 + 512 + ch * 256 + lane * 4,
                            (char*)&Zs[r * 256]);
            }
            __syncthreads();
#pragma unroll
            for (int k4 = 0; k4 < 20; k4 += 4) {
                float4 av4[7];
#pragma unroll
                for (int i = 0; i < 7; i++)
                    av4[i] = *(const float4*)&A_lds[(ty * 7 + i) * 108 + kt * 20 + k4];
#pragma unroll
                for (int kk = 0; kk < 4; kk++) {
                    int k2 = k4 + kk;
                    float4 z0 = *(const float4*)&Zs[k2 * 256 + tx * 4];
                    float4 z1 = *(const float4*)&Zs[k2 * 256 + tx * 4 + 128];
                    float zv[8] = {z0.x, z0.y, z0.z, z0.w, z1.x, z1.y, z1.z, z1.w};
#pragma unroll
                    for (int i = 0; i < 7; i++) {
                        float a = ((const float*)&av4[i])[kk];
#pragma unroll
                        for (int j = 0; j < 8; j++)
                            acc2[i][j] = fmaf(a, zv[j], acc2[i][j]);
                    }
                }
            }
        }

        float ccv[8];
#pragma unroll
        for (int j = 0; j < 8; j++) {
            int c = (j < 4) ? (tx * 4 + j) : (tx * 4 + 128 + (j - 4));
            ccv[j] = cc[ch * 256 + c];
        }
        float psum[8], psq[8];
#pragma unroll
        for (int j = 0; j < 8; j++) { psum[j] = 0.f; psq[j] = 0.f; }
#pragma unroll
        for (int i = 0; i < 7; i++) {
            int r = ty * 7 + i;
            if (r >= 50) continue;
            float* orow = TZ + (size_t)(row0 + r) * 1024 + ch * 256;
            float4 o0, o1;
            o0.x = acc2[i][0] + ccv[0]; o0.y = acc2[i][1] + ccv[1];
            o0.z = acc2[i][2] + ccv[2]; o0.w = acc2[i][3] + ccv[3];
            o1.x = acc2[i][4] + ccv[4]; o1.y = acc2[i][5] + ccv[5];
            o1.z = acc2[i][6] + ccv[6]; o1.w = acc2[i][7] + ccv[7];
            *(float4*)(orow + tx * 4) = o0;
            *(float4*)(orow + tx * 4 + 128) = o1;
            psum[0] += o0.x; psq[0] += o0.x * o0.x;
            psum[1] += o0.y; psq[1] += o0.y * o0.y;
            psum[2] += o0.z; psq[2] += o0.z * o0.z;
            psum[3] += o0.w; psq[3] += o0.w * o0.w;
            psum[4] += o1.x; psq[4] += o1.x * o1.x;
            psum[5] += o1.y; psq[5] += o1.y * o1.y;
            psum[6] += o1.z; psq[6] += o1.z * o1.z;
            psum[7] += o1.w; psq[7] += o1.w * o1.w;
        }
        // deterministic BN partial reduction (reuse Zs as sums[8][2][256])
        __syncthreads();
        float* sums = Zs;
#pragma unroll
        for (int j = 0; j < 8; j++) {
            int c = (j < 4) ? (tx * 4 + j) : (tx * 4 + 128 + (j - 4));
            sums[ty * 512 + c] = psum[j];
            sums[ty * 512 + 256 + c] = psq[j];
        }
        __syncthreads();
        {
            float ssv = 0.f, sqv = 0.f;
            for (int y = 0; y < 8; y++) {
                ssv += sums[y * 512 + tid];
                sqv += sums[y * 512 + 256 + tid];
            }
            part[(size_t)pair * 1024 + ch * 256 + tid] = ssv;
            part[(size_t)pair * 1024 + 512 + ch * 256 + tid] = sqv;
        }
    }
}

// ---------------- finalize channel-BN from partials: grid 512, block 64 ----------------
__global__ void wy_fin2_kernel(const float* __restrict__ part,
                               const float* __restrict__ g, const float* __restrict__ bb,
                               float* __restrict__ s, float* __restrict__ t) {
    int c = blockIdx.x;
    int l = threadIdx.x; // 64
    float sum = 0.f, sq = 0.f;
    for (int p = l; p < 512; p += 64) {
        sum += part[(size_t)p * 1024 + c];
        sq  += part[(size_t)p * 1024 + 512 + c];
    }
    for (int off = 32; off > 0; off >>= 1) {
        sum += __shfl_xor(sum, off, 64);
        sq  += __shfl_xor(sq, off, 64);
    }
    if (l == 0) {
        float m   = sum / BN_ROWS;
        float var = sq / BN_ROWS - m * m;
        float sc  = g[c] * rsqrtf(var + EPS);
        s[c] = sc;
        t[c] = bb[c] - m * sc;
    }
}

// ---------------- residual: V += Wy*s[c] + t[c] (Wy strided in TZ) ----------------
__global__ void residual_kernel(float* __restrict__ V, const float* __restrict__ Wy, int ldw,
                                const float* __restrict__ s, const float* __restrict__ t) {
    size_t total4 = (size_t)BN_ROWS * Cc / 4;
    for (size_t i4 = (size_t)blockIdx.x * blockDim.x + threadIdx.x; i4 < total4;
         i4 += (size_t)gridDim.x * blockDim.x) {
        int row = (int)(i4 >> 7);
        int c = (int)(i4 & 127) * 4;
        float4 w = *(const float4*)(Wy + (size_t)row * ldw + c);
        float4 sv = *(const float4*)(s + c);
        float4 tv = *(const float4*)(t + c);
        float4 v = *(float4*)(V + (size_t)row * Cc + c);
        v.x += w.x * sv.x + tv.x; v.y += w.y * sv.y + tv.y;
        v.z += w.z * sv.z + tv.z; v.w += w.w * sv.w + tv.w;
        *(float4*)(V + (size_t)row * Cc + c) = v;
    }
}

// ---------------- l2norm over node dim + mean, final residual folded ----------------
__global__ void l2norm_mean_kernel(const float* __restrict__ V, const float* __restrict__ TZwy,
                                   const float* __restrict__ s, const float* __restrict__ t,
                                   float* __restrict__ ALL) {
    int b = blockIdx.x;
    int c = threadIdx.x; // 512
    float sc = s[c], sh = t[c];
    float sum = 0.f, sq = 0.f;
    const float* p = V + (size_t)b * Nn * Cc + c;
    const float* w = TZwy + (size_t)b * Nn * 1024 + c;
    for (int n = 0; n < Nn; n++) {
        float v = p[(size_t)n * Cc] + w[(size_t)n * 1024] * sc + sh;
        sum += v; sq += v * v;
    }
    ALL[(size_t)b * 1536 + 512 + c] = sum / (Nn * sqrtf(sq));
}

// ---------------- final: BN(all_feats) @ ff_w.T + ff_b -> (256,2) ----------------
__global__ void final_kernel(const float* __restrict__ ALL, const float* __restrict__ s,
                             const float* __restrict__ t, const float* __restrict__ w,
                             const float* __restrict__ bias, float* __restrict__ out) {
    int b = blockIdx.x;
    int tid = threadIdx.x; // 256
    float p0 = 0.f, p1 = 0.f;
    for (int k = tid; k < 1536; k += 256) {
        float af = ALL[(size_t)b * 1536 + k] * s[k] + t[k];
        p0 += af * w[k];
        p1 += af * w[1536 + k];
    }
    __shared__ float s0[256], s1[256];
    s0[tid] = p0; s1[tid] = p1;
    __syncthreads();
    for (int off = 128; off > 0; off >>= 1) {
        if (tid < off) { s0[tid] += s0[tid + off]; s1[tid] += s1[tid + off]; }
        __syncthreads();
    }
    if (tid == 0) {
        out[b * 2 + 0] = s0[0] + bias[0];
        out[b * 2 + 1] = s1[0] + bias[1];
    }
}

extern "C" void kernel_launch(void* const* d_in, const int* in_sizes, int n_in,
                              void* d_out, int out_size, void* d_ws, size_t ws_size,
                              hipStream_t stream) {
    const float* img   = (const float*)d_in[0];
    const float* txt   = (const float*)d_in[1];
    const float* node  = (const float*)d_in[2];
    const float* pos   = (const float*)d_in[3];
    const float* swinbn_g = (const float*)d_in[4];
    const float* swinbn_b = (const float*)d_in[5];
    const float* swinfc_w = (const float*)d_in[6];
    const float* swinfc_b = (const float*)d_in[7];
    const float* bntext_g = (const float*)d_in[8];
    const float* bntext_b = (const float*)d_in[9];
    const float* fctext_w = (const float*)d_in[10];
    const float* fctext_b = (const float*)d_in[11];
    const float* bngat_g  = (const float*)d_in[12];
    const float* bngat_b  = (const float*)d_in[13];
    const float* fcgat_w  = (const float*)d_in[14];
    const float* fcgat_b  = (const float*)d_in[15];
    const float* bnbbox_g = (const float*)d_in[16];
    const float* bnbbox_b = (const float*)d_in[17];
    const float* fcbbox_w = (const float*)d_in[18];
    const float* fcbbox_b = (const float*)d_in[19];
    const float* gcn_theta_w = (const float*)d_in[20];
    const float* gcn_theta_b = (const float*)d_in[21];
    const float* gcn_phi_w   = (const float*)d_in[22];
    const float* gcn_phi_b   = (const float*)d_in[23];
    const float* gcn_g_w     = (const float*)d_in[24];
    const float* gcn_g_b     = (const float*)d_in[25];
    const float* gcn_W_w     = (const float*)d_in[26];
    const float* gcn_W_b     = (const float*)d_in[27];
    const float* gcn_bn_g    = (const float*)d_in[28];
    const float* gcn_bn_b    = (const float*)d_in[29];
    const float* ffbn_g = (const float*)d_in[30];
    const float* ffbn_b = (const float*)d_in[31];
    const float* ff_w   = (const float*)d_in[32];
    const float* ff_b   = (const float*)d_in[33];

    float* ws = (float*)d_ws;
    const size_t VN = (size_t)BN_ROWS * Cc;          // 13,107,200
    const size_t CC2 = (size_t)Cc * Cc;              // 262,144
    float* V       = ws;                              // VN
    float* TZ      = V + VN;                          // 2*VN (25600 x 1024)
    float* Mw_all  = TZ + 2 * VN;                     // 8*CC2
    float* WGT_all = Mw_all + 8 * CC2;                // 8*CC2
    float* WT      = WGT_all + 8 * CC2;               // 393,216
    float* ALL     = WT + 393216;                     // 393,216
    float* part    = ALL + (size_t)Bsz * 1536;        // 524,288 (also npart)
    float* q2_all  = part + 524288;                   // 8 x 512
    float* cc_all  = q2_all + 4096;                   // 8 x 512
    float* st      = cc_all + 4096;
    float* s_img = st;            float* t_img = s_img + 1024;
    float* s_txt = t_img + 1024;  float* t_txt = s_txt + 768;
    float* s_nd  = t_txt + 768;   float* t_nd  = s_nd + 128;
    float* s_bb  = t_nd + 128;    float* t_bb  = s_bb + 128;
    float* s_g   = t_bb + 128;    float* t_g   = s_g + 512;
    float* s_ff  = t_g + 512;     float* t_ff  = s_ff + 1536;
    float* pb    = t_ff + 1536;   // 512 padded fcgat bias

    dim3 blk(256);

    // input BN stats
    colstats_kernel<<<1024, 256, 0, stream>>>(img, 256, 1024, swinbn_g, swinbn_b, s_img, t_img);
    colstats_kernel<<<768, 256, 0, stream>>>(txt, 256, 768, bntext_g, bntext_b, s_txt, t_txt);
    chstats_part_kernel<<<dim3(100, 16, 1), 256, 0, stream>>>(node, part);
    chstats_fin_kernel<<<1, 128, 0, stream>>>(part, bngat_g, bngat_b, s_nd, t_nd);
    chstats_kernel<<<100, 256, 0, stream>>>(pos, 4, bnbbox_g, bnbbox_b, s_bb, t_bb);

    // heads
    gemm_kernel<1, true, true><<<dim3(4, 8, 1), blk, 0, stream>>>(
        img, swinfc_w, swinfc_b, s_img, t_img, 256, 512, 1024, 1024, 1024, 0,
        ALL, 1536, 0);
    gemm_kernel<1, true, true><<<dim3(4, 8, 1), blk, 0, stream>>>(
        txt, fctext_w, fctext_b, s_txt, t_txt, 256, 512, 768, 768, 768, 0,
        ALL, 1536, 1024);
    transpose_w_kernel<<<dim3(24, 16, 1), blk, 0, stream>>>(fcgat_w, fcgat_b, WT, pb);
    gemm128_kernel<2, true, false, 32, 2><<<800, blk, 0, stream>>>(
        node, WT, nullptr, 4, pb, s_nd, t_nd,
        25600, 512, 768, 768, 512, 100, V, 512, 0);
    bbox_kernel<<<3200, 256, 0, stream>>>(pos, fcbbox_w, fcbbox_b, s_bb, t_bb, V);

    // all weight-side composes upfront
    compose_kernel<<<dim3(16, 8, 16), blk, 0, stream>>>(
        gcn_theta_w, gcn_phi_w, gcn_g_w, gcn_W_w, Mw_all, WGT_all);
    qc_kernel<<<dim3(512, 16, 1), 64, 0, stream>>>(
        gcn_phi_w, gcn_theta_b, gcn_W_w, gcn_g_b, gcn_W_b, q2_all, cc_all);

    // 8 GCN blocks: gemm -> fused attention -> BN finalize -> residual
    for (int i = 0; i < 8; i++) {
        gemm128_kernel<0, false, false, 32, 3><<<1600, blk, 0, stream>>>(
            V, Mw_all + (size_t)i * CC2, WGT_all + (size_t)i * CC2, 4,
            nullptr, nullptr, nullptr,
            25600, 1024, 512, 512, 512, 0, TZ, 1024, 0);

        attn_fused_kernel<<<512, blk, 0, stream>>>(
            TZ, V, q2_all + (size_t)i * Cc, cc_all + (size_t)i * Cc, part);

        wy_fin2_kernel<<<512, 64, 0, stream>>>(part, gcn_bn_g + (size_t)i * Cc,
                                               gcn_bn_b + (size_t)i * Cc, s_g, t_g);

        if (i < 7)
            residual_kernel<<<4096, 256, 0, stream>>>(V, TZ, 1024, s_g, t_g);
    }

    // l2norm over node dim + mean (last residual folded here)
    l2norm_mean_kernel<<<256, 512, 0, stream>>>(V, TZ, s_g, t_g, ALL);
    // final BN + tiny FC
    colstats_kernel<<<1536, 256, 0, stream>>>(ALL, 256, 1536, ffbn_g, ffbn_b, s_ff, t_ff);
    final_kernel<<<256, 256, 0, stream>>>(ALL, s_ff, t_ff, ff_w, ff_b, (float*)d_out);
}